// Round 18
// baseline (214.164 us; speedup 1.0000x reference)
//
#include <hip/hip_runtime.h>
#include <stdint.h>

#define S_ 8
#define N_ 4096
#define I_ 256
#define L_ 512
#define M_ 256
#define D_ 768   // I + L
#define NT32 24  // 768/32 K-tiles

typedef __bf16 bf16x8 __attribute__((ext_vector_type(8)));
typedef float f32x4 __attribute__((ext_vector_type(4)));
typedef unsigned short ushort_t;

__device__ __forceinline__ unsigned short f2bf(float f) {
  union { float f; uint32_t u; } c; c.f = f;
  uint32_t u = c.u;
  uint32_t r = u + 0x7FFFu + ((u >> 16) & 1u);
  return (unsigned short)(r >> 16);
}

__device__ __forceinline__ float fsigmoid(float x) {
  return 1.0f / (1.0f + __expf(-x));
}
__device__ __forceinline__ float ftanh(float x) {
  float ax = fabsf(x);
  float e = __expf(-2.0f * ax);
  float t = (1.0f - e) / (1.0f + e);
  return copysignf(t, x);
}

#define GLD16(gsrc, ldst)                                                                  \
  __builtin_amdgcn_global_load_lds(                                                        \
      (const __attribute__((address_space(1))) uint32_t*)(uintptr_t)(gsrc),                \
      (__attribute__((address_space(3))) uint32_t*)(uintptr_t)(ldst), 16, 0, 0)

// ---------------- fused prep kernel (verified r13-r17) ----------------
__global__ __launch_bounds__(256) void prep_kernel(
    const float* __restrict__ mod, const float* __restrict__ h0,
    const float* __restrict__ Wi, const float* __restrict__ Wf,
    const float* __restrict__ Wg, const float* __restrict__ Wo,
    const float* __restrict__ Wy, ushort_t* __restrict__ w4,
    ushort_t* __restrict__ wyb, ushort_t* __restrict__ xh) {
  const int y = blockIdx.y;
  int t = blockIdx.x * 256 + threadIdx.x;
  const int stride = gridDim.x * 256;
  if (y < 4) {
    const float* src = (y == 0) ? Wi : (y == 1) ? Wf : (y == 2) ? Wg : Wo;
    ushort_t* dst = w4 + (size_t)y * S_ * L_ * D_;
    const int n4 = S_ * L_ * D_ / 4;
    for (; t < n4; t += stride) {
      float4 v = ((const float4*)src)[t];
      ushort4 o;
      o.x = f2bf(v.x); o.y = f2bf(v.y); o.z = f2bf(v.z); o.w = f2bf(v.w);
      ((ushort4*)dst)[t] = o;
    }
  } else if (y == 4) {
    const int n4 = S_ * M_ * L_ / 4;
    for (; t < n4; t += stride) {
      float4 v = ((const float4*)Wy)[t];
      ushort4 o;
      o.x = f2bf(v.x); o.y = f2bf(v.y); o.z = f2bf(v.z); o.w = f2bf(v.w);
      ((ushort4*)wyb)[t] = o;
    }
  } else if (y == 5) {
    const int total = S_ * N_ * (I_ / 4);
    for (; t < total; t += stride) {
      int r = t >> 6, c = t & 63;
      int s = r >> 12, n = r & (N_ - 1);
      float4 v = *(const float4*)(mod + (size_t)n * (S_ * I_) + s * I_ + c * 4);
      ushort4 o;
      o.x = f2bf(v.x); o.y = f2bf(v.y); o.z = f2bf(v.z); o.w = f2bf(v.w);
      *(ushort4*)(xh + (size_t)r * D_ + c * 4) = o;
    }
  } else {
    const int total = S_ * N_ * (L_ / 4);
    for (; t < total; t += stride) {
      int r = t >> 7, c = t & 127;
      int s = r >> 12, n = r & (N_ - 1);
      float4 v = *(const float4*)(h0 + (size_t)n * (S_ * L_) + s * L_ + c * 4);
      ushort4 o;
      o.x = f2bf(v.x); o.y = f2bf(v.y); o.z = f2bf(v.z); o.w = f2bf(v.w);
      *(ushort4*)(xh + (size_t)r * D_ + I_ + c * 4) = o;
    }
  }
}

// ---------------- gates r18: 2 blocks/CU cross-overlap, register-correct budget ----------------
// 512 thr, 8 waves (wm = w>>2 -> 64 n-rows x2, wl = w&3 -> 16 l-cols), tile 128n x (4g x 64l).
// acc[4][4] = 64 AGPR; VGPR ~56 -> total ~120 <= 128 @ 4 waves/SIMD. LDS 64 KB alloc
// (BK=32 dbuf: A 8K + B 16K per buf, buf1 at +32 KB) -> 2 blocks/CU (128 KB, 16 waves).
// Loop = r13-verified minimal: STAGE(t+1) -> reads+MFMA(t) -> vmcnt(0) -> syncthreads;
// sibling block's MFMA fills this block's stage/barrier shadow (m114).
// Swizzle: r4-verified super-row scheme for 64B rows (slot' = ((row&1)*4+c) ^ ((row>>1)&7)).
// ds_read: r16-style precomputed byte bases (XOR folds into base; rt/g strides immediate).
__global__ __launch_bounds__(512, 4) void gates_kernel(
    const ushort_t* __restrict__ xh,   // [S][N][D] bf16
    const ushort_t* __restrict__ w4,   // [4][S][L][D] bf16
    const float* __restrict__ bi, const float* __restrict__ bff,
    const float* __restrict__ bg, const float* __restrict__ bo,
    const float* __restrict__ c0,      // [N][S*L] f32
    ushort_t* __restrict__ hout)       // [S][N][L] bf16
{
  __shared__ __align__(16) ushort_t smem[32768];  // 64 KB = 2 bufs x 32 KB (A 8K | B 16K | pad)
  const int tid = threadIdx.x;
  const int lane = tid & 63;
  const int ln15 = lane & 15;
  const int ln4 = lane >> 4;          // k-octet 0..3 within K32
  const int w = tid >> 6;             // 0..7
  const int wm = w >> 2;              // 0..1 -> 64 n-rows
  const int wl = w & 3;               // 0..3 -> 16 l-cols

  const int bid = blockIdx.x;         // 2048 blocks
  const int s = bid & 7;              // stream-per-XCD
  const int r = bid >> 3;             // 0..255
  const int n0 = (r >> 3) << 7;       // 32 n-blocks of 128
  const int l0 = (r & 7) << 6;        // 8 l-blocks of 64

  const size_t xh_base = (size_t)(s * N_ + n0) * D_;

  // staging decode (r4-verified super-row swizzle): slot -> (row, k-chunk)
  // A: 512 slots (rows 0..127), 1 round. B: 1024 slots (rows 0..255 = g*64+ll), 2 rounds.
  const ushort_t* aSrc;
  {
    int slot = tid;
    int sr = slot >> 3, ch0 = (slot & 7) ^ (sr & 7);
    int row = (sr << 1) | (ch0 >> 2), c = ch0 & 3;
    aSrc = xh + xh_base + (size_t)row * D_ + (c << 3);
  }
  const ushort_t* bSrc[2];
  #pragma unroll
  for (int rd = 0; rd < 2; ++rd) {
    int slot = tid + (rd << 9);
    int sr = slot >> 3, ch0 = (slot & 7) ^ (sr & 7);
    int row = (sr << 1) | (ch0 >> 2), c = ch0 & 3;
    int g = row >> 6, ll = row & 63;
    bSrc[rd] = w4 + ((size_t)((g * S_ + s) * L_) + l0 + ll) * D_ + (c << 3);
  }

  // STAGE: 3 GLD16/thread. bs = buf slot base (0 or 2048).
#define STAGE(bs, tile) do {                                                            \
    const int k0_ = (tile) << 5;                                                        \
    GLD16(aSrc + k0_, &smem[((bs) + (w << 6)) * 8]);                                    \
    GLD16(bSrc[0] + k0_, &smem[((bs) + 512 + (w << 6)) * 8]);                           \
    GLD16(bSrc[1] + k0_, &smem[((bs) + 1024 + (w << 6)) * 8]);                          \
  } while (0)

  // ds_read byte bases: byte(row,oct) = (row>>1)*128 + ((((row&1)<<2)|oct) ^ ((row>>1)&7))*16
  // row = base + rt*16 (A) / g*64 + wl*16 + ln15 (B); (row>>1)&7 == ln15>>1 for all rt/g.
  const char* smemB = (const char*)smem;
  const uint32_t chk = (uint32_t)(((((ln15 & 1) << 2) | ln4) ^ (ln15 >> 1)) << 4);
  const uint32_t aK = (uint32_t)((wm << 12) + ((ln15 >> 1) << 7)) + chk;
  const uint32_t bK = 8192u + (uint32_t)((wl << 10) + ((ln15 >> 1) << 7)) + chk;

  f32x4 acc[4][4];
  #pragma unroll
  for (int i = 0; i < 4; ++i)
    #pragma unroll
    for (int j = 0; j < 4; ++j) {
      f32x4 z = {0.f, 0.f, 0.f, 0.f};
      acc[i][j] = z;
    }

  STAGE(0, 0);
  asm volatile("s_waitcnt vmcnt(0)" ::: "memory");
  __syncthreads();

  #pragma unroll 1
  for (int t = 0; t < NT32; ++t) {
    const int bsCur = (t & 1) << 11;                 // slot base: 0 / 2048
    const uint32_t curB = (uint32_t)(t & 1) << 15;   // byte base: 0 / 32768
    if (t + 1 < NT32) STAGE(bsCur ^ 2048, t + 1);

    const char* pA = smemB + (aK + curB);
    const char* pB = smemB + (bK + curB);
    bf16x8 a[4], b[4];
    #pragma unroll
    for (int rt = 0; rt < 4; ++rt) a[rt] = *(const bf16x8*)(pA + rt * 1024);
    #pragma unroll
    for (int g = 0; g < 4; ++g) b[g] = *(const bf16x8*)(pB + g * 4096);
    #pragma unroll
    for (int rt = 0; rt < 4; ++rt)
      #pragma unroll
      for (int g = 0; g < 4; ++g)
        acc[rt][g] = __builtin_amdgcn_mfma_f32_16x16x32_bf16(a[rt], b[g], acc[rt][g], 0, 0, 0);

    asm volatile("s_waitcnt vmcnt(0)" ::: "memory");
    __syncthreads();
  }

  // Epilogue (r4-verified): C/D col = lane&15 -> l, row = (lane>>4)*4+j -> n. acc[rt][g].
  const int l = l0 + (wl << 4) + ln15;
  const float vbi = bi[s * L_ + l];
  const float vbf = bff[s * L_ + l];
  const float vbg = bg[s * L_ + l];
  const float vbo = bo[s * L_ + l];
  #pragma unroll
  for (int rt = 0; rt < 4; ++rt) {
    #pragma unroll
    for (int j = 0; j < 4; ++j) {
      const int n = n0 + (wm << 6) + (rt << 4) + (ln4 << 2) + j;
      const float c0v = c0[(size_t)n * (S_ * L_) + s * L_ + l];
      const float iv = fsigmoid(acc[rt][0][j] + vbi);
      const float fv = fsigmoid(acc[rt][1][j] + vbf);
      const float gv = ftanh(acc[rt][2][j] + vbg);
      const float ov = fsigmoid(acc[rt][3][j] + vbo);
      const float cn = fv * c0v + iv * gv;
      const float hn = ov * ftanh(cn);
      hout[(size_t)(s * N_ + n) * L_ + l] = f2bf(hn);
    }
  }
#undef STAGE
}

// ---------------- output GEMM (verified r1-r17) ----------------
__global__ __launch_bounds__(256, 2) void out_kernel(
    const ushort_t* __restrict__ h,    // [S][N][L] bf16
    const ushort_t* __restrict__ wy,   // [S][M][L] bf16
    const float* __restrict__ by,      // [S*M]
    float* __restrict__ out)           // [N][S*M]
{
  __shared__ __align__(16) ushort_t smem[1536 * 8];
  const int tid = threadIdx.x;
  const int lane = tid & 63;
  const int w = tid >> 6;
  const int n0 = blockIdx.x * 128;
  const int m0 = blockIdx.y * 64;
  const int s = blockIdx.z;

  f32x4 acc[2][4];
  #pragma unroll
  for (int rt = 0; rt < 2; ++rt)
    #pragma unroll
    for (int ct = 0; ct < 4; ++ct) {
      f32x4 z = {0.f, 0.f, 0.f, 0.f};
      acc[rt][ct] = z;
    }

  const size_t h_row0 = (size_t)(s * N_ + n0) * L_;

  for (int t = 0; t < L_ / 64; ++t) {
    const int k0 = t * 64;
    #pragma unroll
    for (int it = 0; it < 4; ++it) {
      int chunk = it * 256 + tid;
      int rr = chunk >> 3, c = chunk & 7;
      int cg = c ^ (rr & 7);
      const ushort_t* src = h + h_row0 + (size_t)rr * L_ + k0 + cg * 8;
      GLD16(src, &smem[(it * 256 + w * 64) * 8]);
    }
    #pragma unroll
    for (int it = 0; it < 2; ++it) {
      int chunk = it * 256 + tid;
      int rl = chunk >> 3, c = chunk & 7;
      int cg = c ^ (rl & 7);
      const ushort_t* src = wy + ((size_t)(s * M_ + m0 + rl)) * L_ + k0 + cg * 8;
      GLD16(src, &smem[(1024 + it * 256 + w * 64) * 8]);
    }
    __syncthreads();
    #pragma unroll
    for (int kk = 0; kk < 2; ++kk) {
      const int cc = kk * 4 + (lane >> 4);
      bf16x8 av[2];
      #pragma unroll
      for (int rt = 0; rt < 2; ++rt) {
        int rr = w * 32 + rt * 16 + (lane & 15);
        av[rt] = *(const bf16x8*)&smem[(rr * 8 + (cc ^ (rr & 7))) * 8];
      }
      #pragma unroll
      for (int ct = 0; ct < 4; ++ct) {
        int rl = ct * 16 + (lane & 15);
        bf16x8 b = *(const bf16x8*)&smem[(1024 + rl * 8 + (cc ^ (rl & 7))) * 8];
        acc[0][ct] = __builtin_amdgcn_mfma_f32_16x16x32_bf16(av[0], b, acc[0][ct], 0, 0, 0);
        acc[1][ct] = __builtin_amdgcn_mfma_f32_16x16x32_bf16(av[1], b, acc[1][ct], 0, 0, 0);
      }
    }
    __syncthreads();
  }

  #pragma unroll
  for (int ct = 0; ct < 4; ++ct) {
    const int m = m0 + ct * 16 + (lane & 15);
    const float vb = by[s * M_ + m];
    #pragma unroll
    for (int rt = 0; rt < 2; ++rt) {
      #pragma unroll
      for (int j = 0; j < 4; ++j) {
        const int n = n0 + w * 32 + rt * 16 + (lane >> 4) * 4 + j;
        out[(size_t)n * (S_ * M_) + s * M_ + m] = acc[rt][ct][j] + vb;
      }
    }
  }
}

// ---------------- launcher ----------------

extern "C" void kernel_launch(void* const* d_in, const int* in_sizes, int n_in,
                              void* d_out, int out_size, void* d_ws, size_t ws_size,
                              hipStream_t stream) {
  const float* mod = (const float*)d_in[0];
  const float* h0  = (const float*)d_in[1];
  const float* c0  = (const float*)d_in[2];
  const float* Wi  = (const float*)d_in[3];
  const float* bi  = (const float*)d_in[4];
  const float* Wf  = (const float*)d_in[5];
  const float* bf  = (const float*)d_in[6];
  const float* Wg  = (const float*)d_in[7];
  const float* bg  = (const float*)d_in[8];
  const float* Wo  = (const float*)d_in[9];
  const float* bo  = (const float*)d_in[10];
  const float* Wy  = (const float*)d_in[11];
  const float* by  = (const float*)d_in[12];
  float* out = (float*)d_out;

  ushort_t* ws = (ushort_t*)d_ws;
  ushort_t* xh   = ws;
  ushort_t* w4   = xh  + (size_t)S_ * N_ * D_;
  ushort_t* wyb  = w4  + (size_t)4 * S_ * L_ * D_;
  ushort_t* hbuf = wyb + (size_t)S_ * M_ * L_;

  prep_kernel<<<dim3(768, 7), 256, 0, stream>>>(mod, h0, Wi, Wf, Wg, Wo, Wy, w4, wyb, xh);
  gates_kernel<<<2048, 512, 0, stream>>>(xh, w4, bi, bf, bg, bo, c0, hbuf);
  out_kernel<<<dim3(N_ / 128, M_ / 64, S_), 256, 0, stream>>>(hbuf, wyb, by, out);
}

// Round 19
// 200.337 us; speedup vs baseline: 1.0690x; 1.0690x over previous
//
#include <hip/hip_runtime.h>
#include <stdint.h>

#define S_ 8
#define N_ 4096
#define I_ 256
#define L_ 512
#define M_ 256
#define D_ 768   // I + L
#define NT64 12  // 768/64 K-tiles

typedef __bf16 bf16x8 __attribute__((ext_vector_type(8)));
typedef float f32x4 __attribute__((ext_vector_type(4)));
typedef unsigned short ushort_t;

__device__ __forceinline__ unsigned short f2bf(float f) {
  union { float f; uint32_t u; } c; c.f = f;
  uint32_t u = c.u;
  uint32_t r = u + 0x7FFFu + ((u >> 16) & 1u);
  return (unsigned short)(r >> 16);
}

__device__ __forceinline__ float fsigmoid(float x) {
  return 1.0f / (1.0f + __expf(-x));
}
__device__ __forceinline__ float ftanh(float x) {
  float ax = fabsf(x);
  float e = __expf(-2.0f * ax);
  float t = (1.0f - e) / (1.0f + e);
  return copysignf(t, x);
}

#define GLD16(gsrc, ldst)                                                                  \
  __builtin_amdgcn_global_load_lds(                                                        \
      (const __attribute__((address_space(1))) uint32_t*)(uintptr_t)(gsrc),                \
      (__attribute__((address_space(3))) uint32_t*)(uintptr_t)(ldst), 16, 0, 0)

// ---------------- fused prep kernel (verified r13-r18) ----------------
__global__ __launch_bounds__(256) void prep_kernel(
    const float* __restrict__ mod, const float* __restrict__ h0,
    const float* __restrict__ Wi, const float* __restrict__ Wf,
    const float* __restrict__ Wg, const float* __restrict__ Wo,
    const float* __restrict__ Wy, ushort_t* __restrict__ w4,
    ushort_t* __restrict__ wyb, ushort_t* __restrict__ xh) {
  const int y = blockIdx.y;
  int t = blockIdx.x * 256 + threadIdx.x;
  const int stride = gridDim.x * 256;
  if (y < 4) {
    const float* src = (y == 0) ? Wi : (y == 1) ? Wf : (y == 2) ? Wg : Wo;
    ushort_t* dst = w4 + (size_t)y * S_ * L_ * D_;
    const int n4 = S_ * L_ * D_ / 4;
    for (; t < n4; t += stride) {
      float4 v = ((const float4*)src)[t];
      ushort4 o;
      o.x = f2bf(v.x); o.y = f2bf(v.y); o.z = f2bf(v.z); o.w = f2bf(v.w);
      ((ushort4*)dst)[t] = o;
    }
  } else if (y == 4) {
    const int n4 = S_ * M_ * L_ / 4;
    for (; t < n4; t += stride) {
      float4 v = ((const float4*)Wy)[t];
      ushort4 o;
      o.x = f2bf(v.x); o.y = f2bf(v.y); o.z = f2bf(v.z); o.w = f2bf(v.w);
      ((ushort4*)wyb)[t] = o;
    }
  } else if (y == 5) {
    const int total = S_ * N_ * (I_ / 4);
    for (; t < total; t += stride) {
      int r = t >> 6, c = t & 63;
      int s = r >> 12, n = r & (N_ - 1);
      float4 v = *(const float4*)(mod + (size_t)n * (S_ * I_) + s * I_ + c * 4);
      ushort4 o;
      o.x = f2bf(v.x); o.y = f2bf(v.y); o.z = f2bf(v.z); o.w = f2bf(v.w);
      *(ushort4*)(xh + (size_t)r * D_ + c * 4) = o;
    }
  } else {
    const int total = S_ * N_ * (L_ / 4);
    for (; t < total; t += stride) {
      int r = t >> 7, c = t & 127;
      int s = r >> 12, n = r & (N_ - 1);
      float4 v = *(const float4*)(h0 + (size_t)n * (S_ * L_) + s * L_ + c * 4);
      ushort4 o;
      o.x = f2bf(v.x); o.y = f2bf(v.y); o.z = f2bf(v.z); o.w = f2bf(v.w);
      *(ushort4*)(xh + (size_t)r * D_ + I_ + c * 4) = o;
    }
  }
}

// ---------------- gates r19: r16 (129.7 us, verified) + wave-parity kk-stagger ----------------
// Identical to r16 except the loop body: even waves compute kk0 then kk1, odd waves
// kk1 then kk0 (same staged buffer, pure reorder). At any instant ~half the waves are
// in their ds_read burst while the other half runs MFMAs -> LDS pipe and matrix pipe
// overlap instead of alternating (r16 model: 6.5k cy/iter fully serial; no inter-phase
// barrier exists, the lockstep was LDS round-robin arbitration finishing all waves'
// reads simultaneously).
__global__ __launch_bounds__(1024, 4) void gates_kernel(
    const ushort_t* __restrict__ xh,   // [S][N][D] bf16
    const ushort_t* __restrict__ w4,   // [4][S][L][D] bf16
    const float* __restrict__ bi, const float* __restrict__ bff,
    const float* __restrict__ bg, const float* __restrict__ bo,
    const float* __restrict__ c0,      // [N][S*L] f32
    ushort_t* __restrict__ hout)       // [S][N][L] bf16
{
  __shared__ __align__(16) ushort_t smem[65536];  // 128 KB = 2 x 64 KB buffers
  const int tid = threadIdx.x;
  const int lane = tid & 63;
  const int ln15 = lane & 15;
  const int ln4 = lane >> 4;
  const int w = tid >> 6;             // 0..15
  const int wm = w >> 2;              // 0..3 -> 64 n-rows
  const int wl = w & 3;               // 0..3 -> 16 l-cols

  const int bid = blockIdx.x;
  const int s = bid & 7;              // stream-per-XCD
  const int r = bid >> 3;             // 0..127
  const int n0 = (r >> 3) << 8;
  const int l0 = (r & 7) << 6;

  const size_t xh_base = (size_t)(s * N_ + n0) * D_;

  // staging decode (r1-native swizzle; verified r13/r16)
  const ushort_t* aSrc[2];
  const ushort_t* bSrc[2];
  #pragma unroll
  for (int rd = 0; rd < 2; ++rd) {
    int slot = tid + (rd << 10);
    int row = slot >> 3;
    int cg = (slot & 7) ^ (row & 7);
    aSrc[rd] = xh + xh_base + (size_t)row * D_ + (cg << 3);
    int g = row >> 6, ll = row & 63;
    bSrc[rd] = w4 + ((size_t)((g * S_ + s) * L_) + l0 + ll) * D_ + (cg << 3);
  }

#define STAGE(base, tile) do {                                                          \
    const int k0_ = (tile) << 6;                                                        \
    GLD16(aSrc[0] + k0_, &smem[((base) + (w << 6)) * 8]);                               \
    GLD16(aSrc[1] + k0_, &smem[((base) + 1024 + (w << 6)) * 8]);                        \
    GLD16(bSrc[0] + k0_, &smem[((base) + 2048 + (w << 6)) * 8]);                        \
    GLD16(bSrc[1] + k0_, &smem[((base) + 3072 + (w << 6)) * 8]);                        \
  } while (0)

  // precomputed per-lane LDS byte offsets (r16-verified)
  const char* smemB = (const char*)smem;
  const uint32_t chk0 = (uint32_t)((ln4 ^ (ln15 & 7)) << 4);
  const uint32_t chk1 = (uint32_t)(((4 + ln4) ^ (ln15 & 7)) << 4);
  const uint32_t aBase = (uint32_t)(((wm << 6) + ln15) << 7);
  const uint32_t bBase = 32768u + (uint32_t)(((wl << 4) + ln15) << 7);
  const uint32_t aK0 = aBase + chk0, aK1 = aBase + chk1;
  const uint32_t bK0 = bBase + chk0, bK1 = bBase + chk1;

  f32x4 acc[4][4];
  #pragma unroll
  for (int i = 0; i < 4; ++i)
    #pragma unroll
    for (int j = 0; j < 4; ++j) {
      f32x4 z = {0.f, 0.f, 0.f, 0.f};
      acc[i][j] = z;
    }

#define COMPUTE(pA, pB) do {                                                            \
    bf16x8 a_[4], b_[4];                                                                \
    _Pragma("unroll")                                                                   \
    for (int rt_ = 0; rt_ < 4; ++rt_) a_[rt_] = *(const bf16x8*)((pA) + rt_ * 2048);    \
    _Pragma("unroll")                                                                   \
    for (int g_ = 0; g_ < 4; ++g_) b_[g_] = *(const bf16x8*)((pB) + g_ * 8192);         \
    _Pragma("unroll")                                                                   \
    for (int rt_ = 0; rt_ < 4; ++rt_)                                                   \
      _Pragma("unroll")                                                                 \
      for (int g_ = 0; g_ < 4; ++g_)                                                    \
        acc[rt_][g_] = __builtin_amdgcn_mfma_f32_16x16x32_bf16(                         \
            a_[rt_], b_[g_], acc[rt_][g_], 0, 0, 0);                                    \
  } while (0)

  STAGE(0, 0);
  asm volatile("s_waitcnt vmcnt(0)" ::: "memory");
  __syncthreads();

  #pragma unroll 1
  for (int t = 0; t < NT64; ++t) {
    const int cur = (t & 1) << 12;                  // slot units (STAGE)
    const uint32_t curB = (uint32_t)(t & 1) << 16;  // byte units (ds_read bases)
    if (t + 1 < NT64) STAGE(cur ^ 4096, t + 1);

    const char* pA0 = smemB + (aK0 + curB);
    const char* pA1 = smemB + (aK1 + curB);
    const char* pB0 = smemB + (bK0 + curB);
    const char* pB1 = smemB + (bK1 + curB);

    if (w & 1) {          // odd waves: kk1 first -> phase-staggered vs even waves
      COMPUTE(pA1, pB1);
      COMPUTE(pA0, pB0);
    } else {              // even waves: kk0 first
      COMPUTE(pA0, pB0);
      COMPUTE(pA1, pB1);
    }

    asm volatile("s_waitcnt vmcnt(0)" ::: "memory");
    __syncthreads();
  }

  // Epilogue (r4/r13/r16-verified): C/D col = lane&15 -> l, row = (lane>>4)*4+j -> n.
  const int l = l0 + (wl << 4) + ln15;
  const float vbi = bi[s * L_ + l];
  const float vbf = bff[s * L_ + l];
  const float vbg = bg[s * L_ + l];
  const float vbo = bo[s * L_ + l];
  #pragma unroll
  for (int rt = 0; rt < 4; ++rt) {
    #pragma unroll
    for (int j = 0; j < 4; ++j) {
      const int n = n0 + (wm << 6) + (rt << 4) + (ln4 << 2) + j;
      const float c0v = c0[(size_t)n * (S_ * L_) + s * L_ + l];
      const float iv = fsigmoid(acc[rt][0][j] + vbi);
      const float fv = fsigmoid(acc[rt][1][j] + vbf);
      const float gv = ftanh(acc[rt][2][j] + vbg);
      const float ov = fsigmoid(acc[rt][3][j] + vbo);
      const float cn = fv * c0v + iv * gv;
      const float hn = ov * ftanh(cn);
      hout[(size_t)(s * N_ + n) * L_ + l] = f2bf(hn);
    }
  }
#undef STAGE
#undef COMPUTE
}

// ---------------- output GEMM (verified r1-r18) ----------------
__global__ __launch_bounds__(256, 2) void out_kernel(
    const ushort_t* __restrict__ h,    // [S][N][L] bf16
    const ushort_t* __restrict__ wy,   // [S][M][L] bf16
    const float* __restrict__ by,      // [S*M]
    float* __restrict__ out)           // [N][S*M]
{
  __shared__ __align__(16) ushort_t smem[1536 * 8];
  const int tid = threadIdx.x;
  const int lane = tid & 63;
  const int w = tid >> 6;
  const int n0 = blockIdx.x * 128;
  const int m0 = blockIdx.y * 64;
  const int s = blockIdx.z;

  f32x4 acc[2][4];
  #pragma unroll
  for (int rt = 0; rt < 2; ++rt)
    #pragma unroll
    for (int ct = 0; ct < 4; ++ct) {
      f32x4 z = {0.f, 0.f, 0.f, 0.f};
      acc[rt][ct] = z;
    }

  const size_t h_row0 = (size_t)(s * N_ + n0) * L_;

  for (int t = 0; t < L_ / 64; ++t) {
    const int k0 = t * 64;
    #pragma unroll
    for (int it = 0; it < 4; ++it) {
      int chunk = it * 256 + tid;
      int rr = chunk >> 3, c = chunk & 7;
      int cg = c ^ (rr & 7);
      const ushort_t* src = h + h_row0 + (size_t)rr * L_ + k0 + cg * 8;
      GLD16(src, &smem[(it * 256 + w * 64) * 8]);
    }
    #pragma unroll
    for (int it = 0; it < 2; ++it) {
      int chunk = it * 256 + tid;
      int rl = chunk >> 3, c = chunk & 7;
      int cg = c ^ (rl & 7);
      const ushort_t* src = wy + ((size_t)(s * M_ + m0 + rl)) * L_ + k0 + cg * 8;
      GLD16(src, &smem[(1024 + it * 256 + w * 64) * 8]);
    }
    __syncthreads();
    #pragma unroll
    for (int kk = 0; kk < 2; ++kk) {
      const int cc = kk * 4 + (lane >> 4);
      bf16x8 av[2];
      #pragma unroll
      for (int rt = 0; rt < 2; ++rt) {
        int rr = w * 32 + rt * 16 + (lane & 15);
        av[rt] = *(const bf16x8*)&smem[(rr * 8 + (cc ^ (rr & 7))) * 8];
      }
      #pragma unroll
      for (int ct = 0; ct < 4; ++ct) {
        int rl = ct * 16 + (lane & 15);
        bf16x8 b = *(const bf16x8*)&smem[(1024 + rl * 8 + (cc ^ (rl & 7))) * 8];
        acc[0][ct] = __builtin_amdgcn_mfma_f32_16x16x32_bf16(av[0], b, acc[0][ct], 0, 0, 0);
        acc[1][ct] = __builtin_amdgcn_mfma_f32_16x16x32_bf16(av[1], b, acc[1][ct], 0, 0, 0);
      }
    }
    __syncthreads();
  }

  #pragma unroll
  for (int ct = 0; ct < 4; ++ct) {
    const int m = m0 + ct * 16 + (lane & 15);
    const float vb = by[s * M_ + m];
    #pragma unroll
    for (int rt = 0; rt < 2; ++rt) {
      #pragma unroll
      for (int j = 0; j < 4; ++j) {
        const int n = n0 + w * 32 + rt * 16 + (lane >> 4) * 4 + j;
        out[(size_t)n * (S_ * M_) + s * M_ + m] = acc[rt][ct][j] + vb;
      }
    }
  }
}

// ---------------- launcher ----------------

extern "C" void kernel_launch(void* const* d_in, const int* in_sizes, int n_in,
                              void* d_out, int out_size, void* d_ws, size_t ws_size,
                              hipStream_t stream) {
  const float* mod = (const float*)d_in[0];
  const float* h0  = (const float*)d_in[1];
  const float* c0  = (const float*)d_in[2];
  const float* Wi  = (const float*)d_in[3];
  const float* bi  = (const float*)d_in[4];
  const float* Wf  = (const float*)d_in[5];
  const float* bf  = (const float*)d_in[6];
  const float* Wg  = (const float*)d_in[7];
  const float* bg  = (const float*)d_in[8];
  const float* Wo  = (const float*)d_in[9];
  const float* bo  = (const float*)d_in[10];
  const float* Wy  = (const float*)d_in[11];
  const float* by  = (const float*)d_in[12];
  float* out = (float*)d_out;

  ushort_t* ws = (ushort_t*)d_ws;
  ushort_t* xh   = ws;
  ushort_t* w4   = xh  + (size_t)S_ * N_ * D_;
  ushort_t* wyb  = w4  + (size_t)4 * S_ * L_ * D_;
  ushort_t* hbuf = wyb + (size_t)S_ * M_ * L_;

  prep_kernel<<<dim3(768, 7), 256, 0, stream>>>(mod, h0, Wi, Wf, Wg, Wo, Wy, w4, wyb, xh);
  gates_kernel<<<1024, 1024, 0, stream>>>(xh, w4, bi, bf, bg, bo, c0, hbuf);
  out_kernel<<<dim3(N_ / 128, M_ / 64, S_), 256, 0, stream>>>(hbuf, wyb, by, out);
}

// Round 20
// 195.725 us; speedup vs baseline: 1.0942x; 1.0236x over previous
//
#include <hip/hip_runtime.h>
#include <stdint.h>

#define S_ 8
#define N_ 4096
#define I_ 256
#define L_ 512
#define M_ 256
#define D_ 768   // I + L
#define NT64 12  // 768/64 K-tiles

typedef __bf16 bf16x8 __attribute__((ext_vector_type(8)));
typedef float f32x4 __attribute__((ext_vector_type(4)));
typedef unsigned short ushort_t;

__device__ __forceinline__ unsigned short f2bf(float f) {
  union { float f; uint32_t u; } c; c.f = f;
  uint32_t u = c.u;
  uint32_t r = u + 0x7FFFu + ((u >> 16) & 1u);
  return (unsigned short)(r >> 16);
}

__device__ __forceinline__ float fsigmoid(float x) {
  return 1.0f / (1.0f + __expf(-x));
}
__device__ __forceinline__ float ftanh(float x) {
  float ax = fabsf(x);
  float e = __expf(-2.0f * ax);
  float t = (1.0f - e) / (1.0f + e);
  return copysignf(t, x);
}

#define GLD16(gsrc, ldst)                                                                  \
  __builtin_amdgcn_global_load_lds(                                                        \
      (const __attribute__((address_space(1))) uint32_t*)(uintptr_t)(gsrc),                \
      (__attribute__((address_space(3))) uint32_t*)(uintptr_t)(ldst), 16, 0, 0)

// ---------------- fused prep kernel (verified r13-r19) ----------------
__global__ __launch_bounds__(256) void prep_kernel(
    const float* __restrict__ mod, const float* __restrict__ h0,
    const float* __restrict__ Wi, const float* __restrict__ Wf,
    const float* __restrict__ Wg, const float* __restrict__ Wo,
    const float* __restrict__ Wy, ushort_t* __restrict__ w4,
    ushort_t* __restrict__ wyb, ushort_t* __restrict__ xh) {
  const int y = blockIdx.y;
  int t = blockIdx.x * 256 + threadIdx.x;
  const int stride = gridDim.x * 256;
  if (y < 4) {
    const float* src = (y == 0) ? Wi : (y == 1) ? Wf : (y == 2) ? Wg : Wo;
    ushort_t* dst = w4 + (size_t)y * S_ * L_ * D_;
    const int n4 = S_ * L_ * D_ / 4;
    for (; t < n4; t += stride) {
      float4 v = ((const float4*)src)[t];
      ushort4 o;
      o.x = f2bf(v.x); o.y = f2bf(v.y); o.z = f2bf(v.z); o.w = f2bf(v.w);
      ((ushort4*)dst)[t] = o;
    }
  } else if (y == 4) {
    const int n4 = S_ * M_ * L_ / 4;
    for (; t < n4; t += stride) {
      float4 v = ((const float4*)Wy)[t];
      ushort4 o;
      o.x = f2bf(v.x); o.y = f2bf(v.y); o.z = f2bf(v.z); o.w = f2bf(v.w);
      ((ushort4*)wyb)[t] = o;
    }
  } else if (y == 5) {
    const int total = S_ * N_ * (I_ / 4);
    for (; t < total; t += stride) {
      int r = t >> 6, c = t & 63;
      int s = r >> 12, n = r & (N_ - 1);
      float4 v = *(const float4*)(mod + (size_t)n * (S_ * I_) + s * I_ + c * 4);
      ushort4 o;
      o.x = f2bf(v.x); o.y = f2bf(v.y); o.z = f2bf(v.z); o.w = f2bf(v.w);
      *(ushort4*)(xh + (size_t)r * D_ + c * 4) = o;
    }
  } else {
    const int total = S_ * N_ * (L_ / 4);
    for (; t < total; t += stride) {
      int r = t >> 7, c = t & 127;
      int s = r >> 12, n = r & (N_ - 1);
      float4 v = *(const float4*)(h0 + (size_t)n * (S_ * L_) + s * L_ + c * 4);
      ushort4 o;
      o.x = f2bf(v.x); o.y = f2bf(v.y); o.z = f2bf(v.z); o.w = f2bf(v.w);
      *(ushort4*)(xh + (size_t)r * D_ + I_ + c * 4) = o;
    }
  }
}

// ---------------- gates r20: r16 (129.7 us, verified) + s_setprio around MFMA ----------------
// Identical to r16 except setprio(1)...(0) wrapping the MFMA region. r16's loop has no
// intra-iteration barrier, so waves naturally occupy different phases (ds_read burst vs
// MFMA burst) -> T5's role-diversity prerequisite holds (unlike barrier-locked r5/r6
// where setprio was neutral). Mechanism: CU scheduler favors MFMA-phase waves, letting
// the matrix pipe stay fed while read-phase waves queue LDS requests.
__global__ __launch_bounds__(1024, 4) void gates_kernel(
    const ushort_t* __restrict__ xh,   // [S][N][D] bf16
    const ushort_t* __restrict__ w4,   // [4][S][L][D] bf16
    const float* __restrict__ bi, const float* __restrict__ bff,
    const float* __restrict__ bg, const float* __restrict__ bo,
    const float* __restrict__ c0,      // [N][S*L] f32
    ushort_t* __restrict__ hout)       // [S][N][L] bf16
{
  __shared__ __align__(16) ushort_t smem[65536];  // 128 KB = 2 x 64 KB buffers
  const int tid = threadIdx.x;
  const int lane = tid & 63;
  const int ln15 = lane & 15;
  const int ln4 = lane >> 4;
  const int w = tid >> 6;             // 0..15
  const int wm = w >> 2;              // 0..3 -> 64 n-rows
  const int wl = w & 3;               // 0..3 -> 16 l-cols

  const int bid = blockIdx.x;
  const int s = bid & 7;              // stream-per-XCD
  const int r = bid >> 3;             // 0..127
  const int n0 = (r >> 3) << 8;
  const int l0 = (r & 7) << 6;

  const size_t xh_base = (size_t)(s * N_ + n0) * D_;

  // staging decode (r1-native swizzle; verified r13/r16)
  const ushort_t* aSrc[2];
  const ushort_t* bSrc[2];
  #pragma unroll
  for (int rd = 0; rd < 2; ++rd) {
    int slot = tid + (rd << 10);
    int row = slot >> 3;
    int cg = (slot & 7) ^ (row & 7);
    aSrc[rd] = xh + xh_base + (size_t)row * D_ + (cg << 3);
    int g = row >> 6, ll = row & 63;
    bSrc[rd] = w4 + ((size_t)((g * S_ + s) * L_) + l0 + ll) * D_ + (cg << 3);
  }

#define STAGE(base, tile) do {                                                          \
    const int k0_ = (tile) << 6;                                                        \
    GLD16(aSrc[0] + k0_, &smem[((base) + (w << 6)) * 8]);                               \
    GLD16(aSrc[1] + k0_, &smem[((base) + 1024 + (w << 6)) * 8]);                        \
    GLD16(bSrc[0] + k0_, &smem[((base) + 2048 + (w << 6)) * 8]);                        \
    GLD16(bSrc[1] + k0_, &smem[((base) + 3072 + (w << 6)) * 8]);                        \
  } while (0)

  // precomputed per-lane LDS byte offsets (r16-verified)
  const char* smemB = (const char*)smem;
  const uint32_t chk0 = (uint32_t)((ln4 ^ (ln15 & 7)) << 4);
  const uint32_t chk1 = (uint32_t)(((4 + ln4) ^ (ln15 & 7)) << 4);
  const uint32_t aBase = (uint32_t)(((wm << 6) + ln15) << 7);
  const uint32_t bBase = 32768u + (uint32_t)(((wl << 4) + ln15) << 7);
  const uint32_t aK0 = aBase + chk0, aK1 = aBase + chk1;
  const uint32_t bK0 = bBase + chk0, bK1 = bBase + chk1;

  f32x4 acc[4][4];
  #pragma unroll
  for (int i = 0; i < 4; ++i)
    #pragma unroll
    for (int j = 0; j < 4; ++j) {
      f32x4 z = {0.f, 0.f, 0.f, 0.f};
      acc[i][j] = z;
    }

  STAGE(0, 0);
  asm volatile("s_waitcnt vmcnt(0)" ::: "memory");
  __syncthreads();

  #pragma unroll 1
  for (int t = 0; t < NT64; ++t) {
    const int cur = (t & 1) << 12;            // slot units (STAGE)
    const uint32_t curB = (uint32_t)(t & 1) << 16;  // byte units (ds_read bases)
    if (t + 1 < NT64) STAGE(cur ^ 4096, t + 1);

    const char* pA0 = smemB + (aK0 + curB);
    const char* pA1 = smemB + (aK1 + curB);
    const char* pB0 = smemB + (bK0 + curB);
    const char* pB1 = smemB + (bK1 + curB);

    // kk = 0
    {
      bf16x8 a[4], b[4];
      #pragma unroll
      for (int rt = 0; rt < 4; ++rt) a[rt] = *(const bf16x8*)(pA0 + rt * 2048);
      #pragma unroll
      for (int g = 0; g < 4; ++g) b[g] = *(const bf16x8*)(pB0 + g * 8192);
      __builtin_amdgcn_s_setprio(1);
      #pragma unroll
      for (int rt = 0; rt < 4; ++rt)
        #pragma unroll
        for (int g = 0; g < 4; ++g)
          acc[rt][g] = __builtin_amdgcn_mfma_f32_16x16x32_bf16(a[rt], b[g], acc[rt][g], 0, 0, 0);
      __builtin_amdgcn_s_setprio(0);
    }
    // kk = 1
    {
      bf16x8 a[4], b[4];
      #pragma unroll
      for (int rt = 0; rt < 4; ++rt) a[rt] = *(const bf16x8*)(pA1 + rt * 2048);
      #pragma unroll
      for (int g = 0; g < 4; ++g) b[g] = *(const bf16x8*)(pB1 + g * 8192);
      __builtin_amdgcn_s_setprio(1);
      #pragma unroll
      for (int rt = 0; rt < 4; ++rt)
        #pragma unroll
        for (int g = 0; g < 4; ++g)
          acc[rt][g] = __builtin_amdgcn_mfma_f32_16x16x32_bf16(a[rt], b[g], acc[rt][g], 0, 0, 0);
      __builtin_amdgcn_s_setprio(0);
    }

    asm volatile("s_waitcnt vmcnt(0)" ::: "memory");
    __syncthreads();
  }

  // Epilogue (r4/r13/r16-verified): C/D col = lane&15 -> l, row = (lane>>4)*4+j -> n.
  const int l = l0 + (wl << 4) + ln15;
  const float vbi = bi[s * L_ + l];
  const float vbf = bff[s * L_ + l];
  const float vbg = bg[s * L_ + l];
  const float vbo = bo[s * L_ + l];
  #pragma unroll
  for (int rt = 0; rt < 4; ++rt) {
    #pragma unroll
    for (int j = 0; j < 4; ++j) {
      const int n = n0 + (wm << 6) + (rt << 4) + (ln4 << 2) + j;
      const float c0v = c0[(size_t)n * (S_ * L_) + s * L_ + l];
      const float iv = fsigmoid(acc[rt][0][j] + vbi);
      const float fv = fsigmoid(acc[rt][1][j] + vbf);
      const float gv = ftanh(acc[rt][2][j] + vbg);
      const float ov = fsigmoid(acc[rt][3][j] + vbo);
      const float cn = fv * c0v + iv * gv;
      const float hn = ov * ftanh(cn);
      hout[(size_t)(s * N_ + n) * L_ + l] = f2bf(hn);
    }
  }
#undef STAGE
}

// ---------------- out r20: r16 internals + stream-per-XCD grid matching gates ----------------
// 1D grid, s = bid&7 (same mapping as gates) -> each XCD reads the hbuf stream it just
// wrote (4.2 MB/stream, L2-resident) instead of scattering streams across XCDs.
__global__ __launch_bounds__(256, 2) void out_kernel(
    const ushort_t* __restrict__ h,    // [S][N][L] bf16
    const ushort_t* __restrict__ wy,   // [S][M][L] bf16
    const float* __restrict__ by,      // [S*M]
    float* __restrict__ out)           // [N][S*M]
{
  __shared__ __align__(16) ushort_t smem[1536 * 8];
  const int tid = threadIdx.x;
  const int lane = tid & 63;
  const int w = tid >> 6;

  const int bid = blockIdx.x;         // 1024 blocks
  const int s = bid & 7;              // stream-per-XCD (matches gates)
  const int r = bid >> 3;             // 0..127
  const int n0 = (r >> 2) << 7;       // 32 n-blocks of 128
  const int m0 = (r & 3) << 6;        // 4 m-blocks of 64

  f32x4 acc[2][4];
  #pragma unroll
  for (int rt = 0; rt < 2; ++rt)
    #pragma unroll
    for (int ct = 0; ct < 4; ++ct) {
      f32x4 z = {0.f, 0.f, 0.f, 0.f};
      acc[rt][ct] = z;
    }

  const size_t h_row0 = (size_t)(s * N_ + n0) * L_;

  for (int t = 0; t < L_ / 64; ++t) {
    const int k0 = t * 64;
    #pragma unroll
    for (int it = 0; it < 4; ++it) {
      int chunk = it * 256 + tid;
      int rr = chunk >> 3, c = chunk & 7;
      int cg = c ^ (rr & 7);
      const ushort_t* src = h + h_row0 + (size_t)rr * L_ + k0 + cg * 8;
      GLD16(src, &smem[(it * 256 + w * 64) * 8]);
    }
    #pragma unroll
    for (int it = 0; it < 2; ++it) {
      int chunk = it * 256 + tid;
      int rl = chunk >> 3, c = chunk & 7;
      int cg = c ^ (rl & 7);
      const ushort_t* src = wy + ((size_t)(s * M_ + m0 + rl)) * L_ + k0 + cg * 8;
      GLD16(src, &smem[(1024 + it * 256 + w * 64) * 8]);
    }
    __syncthreads();
    #pragma unroll
    for (int kk = 0; kk < 2; ++kk) {
      const int cc = kk * 4 + (lane >> 4);
      bf16x8 av[2];
      #pragma unroll
      for (int rt = 0; rt < 2; ++rt) {
        int rr = w * 32 + rt * 16 + (lane & 15);
        av[rt] = *(const bf16x8*)&smem[(rr * 8 + (cc ^ (rr & 7))) * 8];
      }
      #pragma unroll
      for (int ct = 0; ct < 4; ++ct) {
        int rl = ct * 16 + (lane & 15);
        bf16x8 b = *(const bf16x8*)&smem[(1024 + rl * 8 + (cc ^ (rl & 7))) * 8];
        acc[0][ct] = __builtin_amdgcn_mfma_f32_16x16x32_bf16(av[0], b, acc[0][ct], 0, 0, 0);
        acc[1][ct] = __builtin_amdgcn_mfma_f32_16x16x32_bf16(av[1], b, acc[1][ct], 0, 0, 0);
      }
    }
    __syncthreads();
  }

  #pragma unroll
  for (int ct = 0; ct < 4; ++ct) {
    const int m = m0 + ct * 16 + (lane & 15);
    const float vb = by[s * M_ + m];
    #pragma unroll
    for (int rt = 0; rt < 2; ++rt) {
      #pragma unroll
      for (int j = 0; j < 4; ++j) {
        const int n = n0 + w * 32 + rt * 16 + (lane >> 4) * 4 + j;
        out[(size_t)n * (S_ * M_) + s * M_ + m] = acc[rt][ct][j] + vb;
      }
    }
  }
}

// ---------------- launcher ----------------

extern "C" void kernel_launch(void* const* d_in, const int* in_sizes, int n_in,
                              void* d_out, int out_size, void* d_ws, size_t ws_size,
                              hipStream_t stream) {
  const float* mod = (const float*)d_in[0];
  const float* h0  = (const float*)d_in[1];
  const float* c0  = (const float*)d_in[2];
  const float* Wi  = (const float*)d_in[3];
  const float* bi  = (const float*)d_in[4];
  const float* Wf  = (const float*)d_in[5];
  const float* bf  = (const float*)d_in[6];
  const float* Wg  = (const float*)d_in[7];
  const float* bg  = (const float*)d_in[8];
  const float* Wo  = (const float*)d_in[9];
  const float* bo  = (const float*)d_in[10];
  const float* Wy  = (const float*)d_in[11];
  const float* by  = (const float*)d_in[12];
  float* out = (float*)d_out;

  ushort_t* ws = (ushort_t*)d_ws;
  ushort_t* xh   = ws;
  ushort_t* w4   = xh  + (size_t)S_ * N_ * D_;
  ushort_t* wyb  = w4  + (size_t)4 * S_ * L_ * D_;
  ushort_t* hbuf = wyb + (size_t)S_ * M_ * L_;

  prep_kernel<<<dim3(768, 7), 256, 0, stream>>>(mod, h0, Wi, Wf, Wg, Wo, Wy, w4, wyb, xh);
  gates_kernel<<<1024, 1024, 0, stream>>>(xh, w4, bi, bf, bg, bo, c0, hbuf);
  out_kernel<<<1024, 256, 0, stream>>>(hbuf, wyb, by, out);
}

// Round 21
// 192.610 us; speedup vs baseline: 1.1119x; 1.0162x over previous
//
#include <hip/hip_runtime.h>
#include <stdint.h>

#define S_ 8
#define N_ 4096
#define I_ 256
#define L_ 512
#define M_ 256
#define D_ 768   // I + L
#define NT64 12  // 768/64 K-tiles

typedef __bf16 bf16x8 __attribute__((ext_vector_type(8)));
typedef float f32x4 __attribute__((ext_vector_type(4)));
typedef unsigned short ushort_t;

__device__ __forceinline__ unsigned short f2bf(float f) {
  union { float f; uint32_t u; } c; c.f = f;
  uint32_t u = c.u;
  uint32_t r = u + 0x7FFFu + ((u >> 16) & 1u);
  return (unsigned short)(r >> 16);
}

__device__ __forceinline__ float fsigmoid(float x) {
  return 1.0f / (1.0f + __expf(-x));
}
__device__ __forceinline__ float ftanh(float x) {
  float ax = fabsf(x);
  float e = __expf(-2.0f * ax);
  float t = (1.0f - e) / (1.0f + e);
  return copysignf(t, x);
}

#define GLD16(gsrc, ldst)                                                                  \
  __builtin_amdgcn_global_load_lds(                                                        \
      (const __attribute__((address_space(1))) uint32_t*)(uintptr_t)(gsrc),                \
      (__attribute__((address_space(3))) uint32_t*)(uintptr_t)(ldst), 16, 0, 0)

// ---------------- fused prep kernel (verified r13-r20) ----------------
__global__ __launch_bounds__(256) void prep_kernel(
    const float* __restrict__ mod, const float* __restrict__ h0,
    const float* __restrict__ Wi, const float* __restrict__ Wf,
    const float* __restrict__ Wg, const float* __restrict__ Wo,
    const float* __restrict__ Wy, ushort_t* __restrict__ w4,
    ushort_t* __restrict__ wyb, ushort_t* __restrict__ xh) {
  const int y = blockIdx.y;
  int t = blockIdx.x * 256 + threadIdx.x;
  const int stride = gridDim.x * 256;
  if (y < 4) {
    const float* src = (y == 0) ? Wi : (y == 1) ? Wf : (y == 2) ? Wg : Wo;
    ushort_t* dst = w4 + (size_t)y * S_ * L_ * D_;
    const int n4 = S_ * L_ * D_ / 4;
    for (; t < n4; t += stride) {
      float4 v = ((const float4*)src)[t];
      ushort4 o;
      o.x = f2bf(v.x); o.y = f2bf(v.y); o.z = f2bf(v.z); o.w = f2bf(v.w);
      ((ushort4*)dst)[t] = o;
    }
  } else if (y == 4) {
    const int n4 = S_ * M_ * L_ / 4;
    for (; t < n4; t += stride) {
      float4 v = ((const float4*)Wy)[t];
      ushort4 o;
      o.x = f2bf(v.x); o.y = f2bf(v.y); o.z = f2bf(v.z); o.w = f2bf(v.w);
      ((ushort4*)wyb)[t] = o;
    }
  } else if (y == 5) {
    const int total = S_ * N_ * (I_ / 4);
    for (; t < total; t += stride) {
      int r = t >> 6, c = t & 63;
      int s = r >> 12, n = r & (N_ - 1);
      float4 v = *(const float4*)(mod + (size_t)n * (S_ * I_) + s * I_ + c * 4);
      ushort4 o;
      o.x = f2bf(v.x); o.y = f2bf(v.y); o.z = f2bf(v.z); o.w = f2bf(v.w);
      *(ushort4*)(xh + (size_t)r * D_ + c * 4) = o;
    }
  } else {
    const int total = S_ * N_ * (L_ / 4);
    for (; t < total; t += stride) {
      int r = t >> 7, c = t & 127;
      int s = r >> 12, n = r & (N_ - 1);
      float4 v = *(const float4*)(h0 + (size_t)n * (S_ * L_) + s * L_ + c * 4);
      ushort4 o;
      o.x = f2bf(v.x); o.y = f2bf(v.y); o.z = f2bf(v.z); o.w = f2bf(v.w);
      *(ushort4*)(xh + (size_t)r * D_ + I_ + c * 4) = o;
    }
  }
}

// ---------------- gates r21 == r16 verbatim (129.7 us, best measured; setprio reverted) ----------------
// 256n x (4g x 64l) tile, 1024 thr, BK=64, 128 KB dbuf LDS, r1-native swizzle,
// STAGE(t+1)->compute(t)->vmcnt(0)->syncthreads, precomputed-offset ds_read addressing.
// Structural plateau: 8 schedule variants (r5/r6/r9/r10 phases, r7 B-in-regs, r17 reg-dbuf,
// r18 2-block, r19 stagger, r20 setprio) all >= this; serial model LDS 3.1k + stage 0.5k
// + MFMA 2.5k + bar 0.6k cy/iter fits every measurement.
__global__ __launch_bounds__(1024, 4) void gates_kernel(
    const ushort_t* __restrict__ xh,   // [S][N][D] bf16
    const ushort_t* __restrict__ w4,   // [4][S][L][D] bf16
    const float* __restrict__ bi, const float* __restrict__ bff,
    const float* __restrict__ bg, const float* __restrict__ bo,
    const float* __restrict__ c0,      // [N][S*L] f32
    ushort_t* __restrict__ hout)       // [S][N][L] bf16
{
  __shared__ __align__(16) ushort_t smem[65536];  // 128 KB = 2 x 64 KB buffers
  const int tid = threadIdx.x;
  const int lane = tid & 63;
  const int ln15 = lane & 15;
  const int ln4 = lane >> 4;
  const int w = tid >> 6;             // 0..15
  const int wm = w >> 2;              // 0..3 -> 64 n-rows
  const int wl = w & 3;               // 0..3 -> 16 l-cols

  const int bid = blockIdx.x;
  const int s = bid & 7;              // stream-per-XCD
  const int r = bid >> 3;             // 0..127
  const int n0 = (r >> 3) << 8;
  const int l0 = (r & 7) << 6;

  const size_t xh_base = (size_t)(s * N_ + n0) * D_;

  // staging decode (r1-native swizzle; verified r13/r16)
  const ushort_t* aSrc[2];
  const ushort_t* bSrc[2];
  #pragma unroll
  for (int rd = 0; rd < 2; ++rd) {
    int slot = tid + (rd << 10);
    int row = slot >> 3;
    int cg = (slot & 7) ^ (row & 7);
    aSrc[rd] = xh + xh_base + (size_t)row * D_ + (cg << 3);
    int g = row >> 6, ll = row & 63;
    bSrc[rd] = w4 + ((size_t)((g * S_ + s) * L_) + l0 + ll) * D_ + (cg << 3);
  }

#define STAGE(base, tile) do {                                                          \
    const int k0_ = (tile) << 6;                                                        \
    GLD16(aSrc[0] + k0_, &smem[((base) + (w << 6)) * 8]);                               \
    GLD16(aSrc[1] + k0_, &smem[((base) + 1024 + (w << 6)) * 8]);                        \
    GLD16(bSrc[0] + k0_, &smem[((base) + 2048 + (w << 6)) * 8]);                        \
    GLD16(bSrc[1] + k0_, &smem[((base) + 3072 + (w << 6)) * 8]);                        \
  } while (0)

  // precomputed per-lane LDS byte offsets (r16-verified)
  const char* smemB = (const char*)smem;
  const uint32_t chk0 = (uint32_t)((ln4 ^ (ln15 & 7)) << 4);
  const uint32_t chk1 = (uint32_t)(((4 + ln4) ^ (ln15 & 7)) << 4);
  const uint32_t aBase = (uint32_t)(((wm << 6) + ln15) << 7);
  const uint32_t bBase = 32768u + (uint32_t)(((wl << 4) + ln15) << 7);
  const uint32_t aK0 = aBase + chk0, aK1 = aBase + chk1;
  const uint32_t bK0 = bBase + chk0, bK1 = bBase + chk1;

  f32x4 acc[4][4];
  #pragma unroll
  for (int i = 0; i < 4; ++i)
    #pragma unroll
    for (int j = 0; j < 4; ++j) {
      f32x4 z = {0.f, 0.f, 0.f, 0.f};
      acc[i][j] = z;
    }

  STAGE(0, 0);
  asm volatile("s_waitcnt vmcnt(0)" ::: "memory");
  __syncthreads();

  #pragma unroll 1
  for (int t = 0; t < NT64; ++t) {
    const int cur = (t & 1) << 12;            // slot units (STAGE)
    const uint32_t curB = (uint32_t)(t & 1) << 16;  // byte units (ds_read bases)
    if (t + 1 < NT64) STAGE(cur ^ 4096, t + 1);

    const char* pA0 = smemB + (aK0 + curB);
    const char* pA1 = smemB + (aK1 + curB);
    const char* pB0 = smemB + (bK0 + curB);
    const char* pB1 = smemB + (bK1 + curB);

    // kk = 0
    {
      bf16x8 a[4], b[4];
      #pragma unroll
      for (int rt = 0; rt < 4; ++rt) a[rt] = *(const bf16x8*)(pA0 + rt * 2048);
      #pragma unroll
      for (int g = 0; g < 4; ++g) b[g] = *(const bf16x8*)(pB0 + g * 8192);
      #pragma unroll
      for (int rt = 0; rt < 4; ++rt)
        #pragma unroll
        for (int g = 0; g < 4; ++g)
          acc[rt][g] = __builtin_amdgcn_mfma_f32_16x16x32_bf16(a[rt], b[g], acc[rt][g], 0, 0, 0);
    }
    // kk = 1
    {
      bf16x8 a[4], b[4];
      #pragma unroll
      for (int rt = 0; rt < 4; ++rt) a[rt] = *(const bf16x8*)(pA1 + rt * 2048);
      #pragma unroll
      for (int g = 0; g < 4; ++g) b[g] = *(const bf16x8*)(pB1 + g * 8192);
      #pragma unroll
      for (int rt = 0; rt < 4; ++rt)
        #pragma unroll
        for (int g = 0; g < 4; ++g)
          acc[rt][g] = __builtin_amdgcn_mfma_f32_16x16x32_bf16(a[rt], b[g], acc[rt][g], 0, 0, 0);
    }

    asm volatile("s_waitcnt vmcnt(0)" ::: "memory");
    __syncthreads();
  }

  // Epilogue (r4/r13/r16-verified): C/D col = lane&15 -> l, row = (lane>>4)*4+j -> n.
  const int l = l0 + (wl << 4) + ln15;
  const float vbi = bi[s * L_ + l];
  const float vbf = bff[s * L_ + l];
  const float vbg = bg[s * L_ + l];
  const float vbo = bo[s * L_ + l];
  #pragma unroll
  for (int rt = 0; rt < 4; ++rt) {
    #pragma unroll
    for (int j = 0; j < 4; ++j) {
      const int n = n0 + (wm << 6) + (rt << 4) + (ln4 << 2) + j;
      const float c0v = c0[(size_t)n * (S_ * L_) + s * L_ + l];
      const float iv = fsigmoid(acc[rt][0][j] + vbi);
      const float fv = fsigmoid(acc[rt][1][j] + vbf);
      const float gv = ftanh(acc[rt][2][j] + vbg);
      const float ov = fsigmoid(acc[rt][3][j] + vbo);
      const float cn = fv * c0v + iv * gv;
      const float hn = ov * ftanh(cn);
      hout[(size_t)(s * N_ + n) * L_ + l] = f2bf(hn);
    }
  }
#undef STAGE
}

// ---------------- out r21 == r20 (stream-per-XCD grid; hbuf L2-resident per XCD) ----------------
__global__ __launch_bounds__(256, 2) void out_kernel(
    const ushort_t* __restrict__ h,    // [S][N][L] bf16
    const ushort_t* __restrict__ wy,   // [S][M][L] bf16
    const float* __restrict__ by,      // [S*M]
    float* __restrict__ out)           // [N][S*M]
{
  __shared__ __align__(16) ushort_t smem[1536 * 8];
  const int tid = threadIdx.x;
  const int lane = tid & 63;
  const int w = tid >> 6;

  const int bid = blockIdx.x;         // 1024 blocks
  const int s = bid & 7;              // stream-per-XCD (matches gates)
  const int r = bid >> 3;             // 0..127
  const int n0 = (r >> 2) << 7;       // 32 n-blocks of 128
  const int m0 = (r & 3) << 6;        // 4 m-blocks of 64

  f32x4 acc[2][4];
  #pragma unroll
  for (int rt = 0; rt < 2; ++rt)
    #pragma unroll
    for (int ct = 0; ct < 4; ++ct) {
      f32x4 z = {0.f, 0.f, 0.f, 0.f};
      acc[rt][ct] = z;
    }

  const size_t h_row0 = (size_t)(s * N_ + n0) * L_;

  for (int t = 0; t < L_ / 64; ++t) {
    const int k0 = t * 64;
    #pragma unroll
    for (int it = 0; it < 4; ++it) {
      int chunk = it * 256 + tid;
      int rr = chunk >> 3, c = chunk & 7;
      int cg = c ^ (rr & 7);
      const ushort_t* src = h + h_row0 + (size_t)rr * L_ + k0 + cg * 8;
      GLD16(src, &smem[(it * 256 + w * 64) * 8]);
    }
    #pragma unroll
    for (int it = 0; it < 2; ++it) {
      int chunk = it * 256 + tid;
      int rl = chunk >> 3, c = chunk & 7;
      int cg = c ^ (rl & 7);
      const ushort_t* src = wy + ((size_t)(s * M_ + m0 + rl)) * L_ + k0 + cg * 8;
      GLD16(src, &smem[(1024 + it * 256 + w * 64) * 8]);
    }
    __syncthreads();
    #pragma unroll
    for (int kk = 0; kk < 2; ++kk) {
      const int cc = kk * 4 + (lane >> 4);
      bf16x8 av[2];
      #pragma unroll
      for (int rt = 0; rt < 2; ++rt) {
        int rr = w * 32 + rt * 16 + (lane & 15);
        av[rt] = *(const bf16x8*)&smem[(rr * 8 + (cc ^ (rr & 7))) * 8];
      }
      #pragma unroll
      for (int ct = 0; ct < 4; ++ct) {
        int rl = ct * 16 + (lane & 15);
        bf16x8 b = *(const bf16x8*)&smem[(1024 + rl * 8 + (cc ^ (rl & 7))) * 8];
        acc[0][ct] = __builtin_amdgcn_mfma_f32_16x16x32_bf16(av[0], b, acc[0][ct], 0, 0, 0);
        acc[1][ct] = __builtin_amdgcn_mfma_f32_16x16x32_bf16(av[1], b, acc[1][ct], 0, 0, 0);
      }
    }
    __syncthreads();
  }

  #pragma unroll
  for (int ct = 0; ct < 4; ++ct) {
    const int m = m0 + ct * 16 + (lane & 15);
    const float vb = by[s * M_ + m];
    #pragma unroll
    for (int rt = 0; rt < 2; ++rt) {
      #pragma unroll
      for (int j = 0; j < 4; ++j) {
        const int n = n0 + w * 32 + rt * 16 + (lane >> 4) * 4 + j;
        out[(size_t)n * (S_ * M_) + s * M_ + m] = acc[rt][ct][j] + vb;
      }
    }
  }
}

// ---------------- launcher ----------------

extern "C" void kernel_launch(void* const* d_in, const int* in_sizes, int n_in,
                              void* d_out, int out_size, void* d_ws, size_t ws_size,
                              hipStream_t stream) {
  const float* mod = (const float*)d_in[0];
  const float* h0  = (const float*)d_in[1];
  const float* c0  = (const float*)d_in[2];
  const float* Wi  = (const float*)d_in[3];
  const float* bi  = (const float*)d_in[4];
  const float* Wf  = (const float*)d_in[5];
  const float* bf  = (const float*)d_in[6];
  const float* Wg  = (const float*)d_in[7];
  const float* bg  = (const float*)d_in[8];
  const float* Wo  = (const float*)d_in[9];
  const float* bo  = (const float*)d_in[10];
  const float* Wy  = (const float*)d_in[11];
  const float* by  = (const float*)d_in[12];
  float* out = (float*)d_out;

  ushort_t* ws = (ushort_t*)d_ws;
  ushort_t* xh   = ws;
  ushort_t* w4   = xh  + (size_t)S_ * N_ * D_;
  ushort_t* wyb  = w4  + (size_t)4 * S_ * L_ * D_;
  ushort_t* hbuf = wyb + (size_t)S_ * M_ * L_;

  prep_kernel<<<dim3(768, 7), 256, 0, stream>>>(mod, h0, Wi, Wf, Wg, Wo, Wy, w4, wyb, xh);
  gates_kernel<<<1024, 1024, 0, stream>>>(xh, w4, bi, bf, bg, bo, c0, hbuf);
  out_kernel<<<1024, 256, 0, stream>>>(hbuf, wyb, by, out);
}